// Round 1
// baseline (233.238 us; speedup 1.0000x reference)
//
#include <hip/hip_runtime.h>
#include <math.h>

#define NB 2
#define NQ 16384        // 32*512 downsampled points per batch
#define NCHUNK 8
#define CHUNK_T 2048    // NQ / NCHUNK targets per chunk
#define OUT_W 512
#define IN_H 64
#define IN_W 2048
#define BIG 1e30f

// ---------------------------------------------------------------------------
// Kernel 1: downsample + pack into SoA float4 (x, y, z, ||p||^2)
// ---------------------------------------------------------------------------
__global__ __launch_bounds__(256) void gather_kernel(
    const float* __restrict__ src_pc,   // [B,64,2048,3]
    const float* __restrict__ tgt_pc,   // [B,3,64,2048]
    float4* __restrict__ src4,          // [B*NQ]
    float4* __restrict__ tgt4)          // [B*NQ]
{
    int gid = blockIdx.x * 256 + threadIdx.x;
    if (gid >= NB * NQ) return;
    int b = gid / NQ;
    int q = gid - b * NQ;
    int oh = q / OUT_W;
    int ow = q - oh * OUT_W;
    int h = oh * 2, w = ow * 4;

    // source: [b][h][w][c] contiguous xyz
    const float* sp = src_pc + (((size_t)b * IN_H + h) * IN_W + w) * 3;
    float sx = sp[0], sy = sp[1], sz = sp[2];
    float ns = sx * sx + sy * sy + sz * sz;
    src4[gid] = make_float4(sx, sy, sz, ns);

    // target: [b][c][h][w], plane stride IN_H*IN_W
    size_t tb = ((size_t)b * 3 * IN_H + h) * IN_W + w;
    float tx = tgt_pc[tb];
    float ty = tgt_pc[tb + (size_t)IN_H * IN_W];
    float tz = tgt_pc[tb + 2 * (size_t)IN_H * IN_W];
    bool valid = (tx != 0.f) || (ty != 0.f) || (tz != 0.f);
    float nt = valid ? (tx * tx + ty * ty + tz * tz) : BIG;  // sentinel: never wins
    if (!valid) { tx = 0.f; ty = 0.f; tz = 0.f; }            // avoid inf-inf NaN
    tgt4[gid] = make_float4(tx, ty, tz, nt);
}

// ---------------------------------------------------------------------------
// Kernel 2: per (batch, target-chunk, query-tile) top-3 smallest d^2
// grid = NB * NCHUNK * (NQ/256) = 1024 blocks of 256 threads
// ---------------------------------------------------------------------------
__global__ __launch_bounds__(256) void knn_main(
    const float4* __restrict__ tgt4,
    const float4* __restrict__ src4,
    float* __restrict__ partial)        // [B*NQ][NCHUNK][3]
{
    __shared__ float4 lt[CHUNK_T];      // 32 KB
    int tid = threadIdx.x;
    int blk = blockIdx.x;
    int qtile = blk & 63;               // NQ/256 = 64
    int chunk = (blk >> 6) & (NCHUNK - 1);
    int b = blk >> 9;                   // / (64*8)

    const float4* tbase = tgt4 + (size_t)b * NQ + (size_t)chunk * CHUNK_T;
    #pragma unroll
    for (int i = tid; i < CHUNK_T; i += 256) lt[i] = tbase[i];
    __syncthreads();

    int q = qtile * 256 + tid;
    float4 s = src4[(size_t)b * NQ + q];
    float b0 = BIG, b1 = BIG, b2 = BIG;

    #pragma unroll 4
    for (int j = 0; j < CHUNK_T; ++j) {
        float4 t = lt[j];
        float base = s.w + t.w;
        float dot = s.x * t.x;
        dot = fmaf(s.y, t.y, dot);
        dot = fmaf(s.z, t.z, dot);
        float v = fmaf(dot, -2.0f, base);   // ||s||^2 + ||t||^2 - 2 s.t
        if (v < b2) {
            if (v < b1) {
                b2 = b1;
                if (v < b0) { b1 = b0; b0 = v; } else { b1 = v; }
            } else {
                b2 = v;
            }
        }
    }

    float* p = partial + ((size_t)(b * NQ + q) * NCHUNK + chunk) * 3;
    p[0] = b0; p[1] = b1; p[2] = b2;
}

// ---------------------------------------------------------------------------
// Kernel 3: merge chunk partials per query, sqrt+clamp, masked block reduce
// ---------------------------------------------------------------------------
__device__ inline void insert3(float v, float& b0, float& b1, float& b2) {
    float t0 = fminf(b0, v); v = fmaxf(b0, v); b0 = t0;
    float t1 = fminf(b1, v); v = fmaxf(b1, v); b1 = t1;
    b2 = fminf(b2, v);
}

__global__ __launch_bounds__(256) void merge_kernel(
    const float* __restrict__ partial,  // [B*NQ][NCHUNK][3]
    const float4* __restrict__ src4,
    float* __restrict__ accum)          // [B][2] : {sum, cnt}
{
    int gid = blockIdx.x * 256 + threadIdx.x;   // < NB*NQ; block spans one batch
    int b = gid >> 14;                          // / NQ

    float b0 = BIG, b1 = BIG, b2 = BIG;
    const float* p = partial + (size_t)gid * (NCHUNK * 3);
    #pragma unroll
    for (int i = 0; i < NCHUNK * 3; ++i) insert3(p[i], b0, b1, b2);

    float4 s = src4[gid];
    float w = ((s.x != 0.f) || (s.y != 0.f) || (s.z != 0.f)) ? 1.f : 0.f;
    float d = fminf(sqrtf(fmaxf(b0, 0.f)), 1e10f)
            + fminf(sqrtf(fmaxf(b1, 0.f)), 1e10f)
            + fminf(sqrtf(fmaxf(b2, 0.f)), 1e10f);
    float dsum = d * w;

    // wave64 reduce
    #pragma unroll
    for (int off = 32; off > 0; off >>= 1) {
        dsum += __shfl_down(dsum, off, 64);
        w    += __shfl_down(w, off, 64);
    }
    __shared__ float sd[4], sw[4];
    int lane = threadIdx.x & 63, wv = threadIdx.x >> 6;
    if (lane == 0) { sd[wv] = dsum; sw[wv] = w; }
    __syncthreads();
    if (threadIdx.x == 0) {
        float td = sd[0] + sd[1] + sd[2] + sd[3];
        float tw = sw[0] + sw[1] + sw[2] + sw[3];
        atomicAdd(&accum[b * 2 + 0], td);
        atomicAdd(&accum[b * 2 + 1], tw);
    }
}

// ---------------------------------------------------------------------------
// Kernel 4: final scalar combine
// ---------------------------------------------------------------------------
__global__ void final_kernel(const float* __restrict__ accum,
                             float* __restrict__ out)
{
    float r = 0.f;
    #pragma unroll
    for (int b = 0; b < NB; ++b)
        r += accum[b * 2] / (3.0f * fmaxf(accum[b * 2 + 1], 1.0f));
    out[0] = r / (float)NB;
}

// ---------------------------------------------------------------------------
extern "C" void kernel_launch(void* const* d_in, const int* in_sizes, int n_in,
                              void* d_out, int out_size, void* d_ws, size_t ws_size,
                              hipStream_t stream) {
    const float* src_pc = (const float*)d_in[0];   // [2,64,2048,3]
    const float* tgt_pc = (const float*)d_in[1];   // [2,3,64,2048]
    float* out = (float*)d_out;

    char* ws = (char*)d_ws;
    float4* tgt4   = (float4*)(ws);                       // 2*16384*16 = 524288 B
    float4* src4   = (float4*)(ws + 524288);              // 524288 B
    float* partial = (float*)(ws + 1048576);              // 32768*24*4 = 3145728 B
    float* accum   = (float*)(ws + 4194304);              // 16 B

    hipMemsetAsync(accum, 0, 4 * sizeof(float), stream);

    gather_kernel<<<(NB * NQ + 255) / 256, 256, 0, stream>>>(src_pc, tgt_pc, src4, tgt4);
    knn_main<<<NB * NCHUNK * (NQ / 256), 256, 0, stream>>>(tgt4, src4, partial);
    merge_kernel<<<NB * NQ / 256, 256, 0, stream>>>(partial, src4, accum);
    final_kernel<<<1, 1, 0, stream>>>(accum, out);
}

// Round 2
// 161.302 us; speedup vs baseline: 1.4460x; 1.4460x over previous
//
#include <hip/hip_runtime.h>
#include <math.h>

#define NB 2
#define NQ 16384        // 32*512 downsampled points per batch
#define NCHUNK 8
#define CHUNK_T 2048    // NQ / NCHUNK targets per chunk
#define OUT_W 512
#define IN_H 64
#define IN_W 2048
#define BIG 1e30f

// ---------------------------------------------------------------------------
// Kernel 1: downsample + pack into SoA float4
//   src4: (x, y, z, ||s||^2)          -- query side
//   tgt4: (-2x, -2y, -2z, ||t||^2)    -- target side, -2 folded for fma chain
// ---------------------------------------------------------------------------
__global__ __launch_bounds__(256) void gather_kernel(
    const float* __restrict__ src_pc,   // [B,64,2048,3]
    const float* __restrict__ tgt_pc,   // [B,3,64,2048]
    float4* __restrict__ src4,          // [B*NQ]
    float4* __restrict__ tgt4)          // [B*NQ]
{
    int gid = blockIdx.x * 256 + threadIdx.x;
    if (gid >= NB * NQ) return;
    int b = gid / NQ;
    int q = gid - b * NQ;
    int oh = q / OUT_W;
    int ow = q - oh * OUT_W;
    int h = oh * 2, w = ow * 4;

    // source: [b][h][w][c] contiguous xyz
    const float* sp = src_pc + (((size_t)b * IN_H + h) * IN_W + w) * 3;
    float sx = sp[0], sy = sp[1], sz = sp[2];
    float ns = sx * sx + sy * sy + sz * sz;
    src4[gid] = make_float4(sx, sy, sz, ns);

    // target: [b][c][h][w], plane stride IN_H*IN_W
    size_t tb = ((size_t)b * 3 * IN_H + h) * IN_W + w;
    float tx = tgt_pc[tb];
    float ty = tgt_pc[tb + (size_t)IN_H * IN_W];
    float tz = tgt_pc[tb + 2 * (size_t)IN_H * IN_W];
    bool valid = (tx != 0.f) || (ty != 0.f) || (tz != 0.f);
    float nt = valid ? (tx * tx + ty * ty + tz * tz) : BIG;  // sentinel: never wins
    if (!valid) { tx = 0.f; ty = 0.f; tz = 0.f; }
    tgt4[gid] = make_float4(-2.f * tx, -2.f * ty, -2.f * tz, nt);
}

// ---------------------------------------------------------------------------
// Kernel 2: per (batch, target-chunk, query-tile) top-3 smallest d^2
// grid = NB * NCHUNK * (NQ/256) = 1024 blocks of 256 threads (4 blocks/CU)
// Inner loop: 8 VALU/pair (1 add + 3 fma dist, min/max/med3/min insert),
// branchless -- no divergence, no exec-mask traffic.
// ---------------------------------------------------------------------------
__global__ __launch_bounds__(256) void knn_main(
    const float4* __restrict__ tgt4,
    const float4* __restrict__ src4,
    float* __restrict__ partial)        // [B*NQ][NCHUNK][3]
{
    __shared__ float4 lt[CHUNK_T];      // 32 KB
    int tid = threadIdx.x;
    int blk = blockIdx.x;
    int qtile = blk & 63;               // NQ/256 = 64
    int chunk = (blk >> 6) & (NCHUNK - 1);
    int b = blk >> 9;                   // / (64*8)

    const float4* tbase = tgt4 + (size_t)b * NQ + (size_t)chunk * CHUNK_T;
    #pragma unroll
    for (int i = tid; i < CHUNK_T; i += 256) lt[i] = tbase[i];
    __syncthreads();

    int q = qtile * 256 + tid;
    float4 s = src4[(size_t)b * NQ + q];
    float b0 = BIG, b1 = BIG, b2 = BIG;

    #pragma unroll 8
    for (int j = 0; j < CHUNK_T; ++j) {
        float4 t = lt[j];                       // broadcast: 0 bank conflicts
        float v = s.w + t.w;                    // ||s||^2 + ||t||^2
        v = fmaf(s.x, t.x, v);                  // t pre-scaled by -2
        v = fmaf(s.y, t.y, v);
        v = fmaf(s.z, t.z, v);
        // branchless sorted-insert of v into (b0 <= b1 <= b2):
        b2 = fminf(b2, fmaxf(b1, v));           // uses old b1
        b1 = __builtin_amdgcn_fmed3f(b0, b1, v);// uses old b0
        b0 = fminf(b0, v);
    }

    float* p = partial + ((size_t)(b * NQ + q) * NCHUNK + chunk) * 3;
    p[0] = b0; p[1] = b1; p[2] = b2;
}

// ---------------------------------------------------------------------------
// Kernel 3: merge chunk partials per query, sqrt+clamp, masked block reduce
// ---------------------------------------------------------------------------
__device__ inline void insert3(float v, float& b0, float& b1, float& b2) {
    b2 = fminf(b2, fmaxf(b1, v));
    b1 = __builtin_amdgcn_fmed3f(b0, b1, v);
    b0 = fminf(b0, v);
}

__global__ __launch_bounds__(256) void merge_kernel(
    const float* __restrict__ partial,  // [B*NQ][NCHUNK][3]
    const float4* __restrict__ src4,
    float* __restrict__ accum)          // [B][2] : {sum, cnt}
{
    int gid = blockIdx.x * 256 + threadIdx.x;   // < NB*NQ; block spans one batch
    int b = gid >> 14;                          // / NQ

    float b0 = BIG, b1 = BIG, b2 = BIG;
    const float* p = partial + (size_t)gid * (NCHUNK * 3);
    #pragma unroll
    for (int i = 0; i < NCHUNK * 3; ++i) insert3(p[i], b0, b1, b2);

    float4 s = src4[gid];
    float w = ((s.x != 0.f) || (s.y != 0.f) || (s.z != 0.f)) ? 1.f : 0.f;
    float d = fminf(sqrtf(fmaxf(b0, 0.f)), 1e10f)
            + fminf(sqrtf(fmaxf(b1, 0.f)), 1e10f)
            + fminf(sqrtf(fmaxf(b2, 0.f)), 1e10f);
    float dsum = d * w;

    // wave64 reduce
    #pragma unroll
    for (int off = 32; off > 0; off >>= 1) {
        dsum += __shfl_down(dsum, off, 64);
        w    += __shfl_down(w, off, 64);
    }
    __shared__ float sd[4], sw[4];
    int lane = threadIdx.x & 63, wv = threadIdx.x >> 6;
    if (lane == 0) { sd[wv] = dsum; sw[wv] = w; }
    __syncthreads();
    if (threadIdx.x == 0) {
        float td = sd[0] + sd[1] + sd[2] + sd[3];
        float tw = sw[0] + sw[1] + sw[2] + sw[3];
        atomicAdd(&accum[b * 2 + 0], td);
        atomicAdd(&accum[b * 2 + 1], tw);
    }
}

// ---------------------------------------------------------------------------
// Kernel 4: final scalar combine
// ---------------------------------------------------------------------------
__global__ void final_kernel(const float* __restrict__ accum,
                             float* __restrict__ out)
{
    float r = 0.f;
    #pragma unroll
    for (int b = 0; b < NB; ++b)
        r += accum[b * 2] / (3.0f * fmaxf(accum[b * 2 + 1], 1.0f));
    out[0] = r / (float)NB;
}

// ---------------------------------------------------------------------------
extern "C" void kernel_launch(void* const* d_in, const int* in_sizes, int n_in,
                              void* d_out, int out_size, void* d_ws, size_t ws_size,
                              hipStream_t stream) {
    const float* src_pc = (const float*)d_in[0];   // [2,64,2048,3]
    const float* tgt_pc = (const float*)d_in[1];   // [2,3,64,2048]
    float* out = (float*)d_out;

    char* ws = (char*)d_ws;
    float4* tgt4   = (float4*)(ws);                       // 524288 B
    float4* src4   = (float4*)(ws + 524288);              // 524288 B
    float* partial = (float*)(ws + 1048576);              // 3145728 B
    float* accum   = (float*)(ws + 4194304);              // 16 B

    hipMemsetAsync(accum, 0, 4 * sizeof(float), stream);

    gather_kernel<<<(NB * NQ + 255) / 256, 256, 0, stream>>>(src_pc, tgt_pc, src4, tgt4);
    knn_main<<<NB * NCHUNK * (NQ / 256), 256, 0, stream>>>(tgt4, src4, partial);
    merge_kernel<<<NB * NQ / 256, 256, 0, stream>>>(partial, src4, accum);
    final_kernel<<<1, 1, 0, stream>>>(accum, out);
}

// Round 3
// 147.297 us; speedup vs baseline: 1.5835x; 1.0951x over previous
//
#include <hip/hip_runtime.h>
#include <math.h>

#define NB 2
#define NQ 16384        // 32*512 downsampled points per batch
#define OUT_W 512
#define IN_H 64
#define IN_W 2048
#define BIG 1e30f
#define QPB 1024        // queries per block = 256 threads * M(4)
#define QTILES (NQ / QPB)   // 16

typedef float float2v __attribute__((ext_vector_type(2)));

__device__ inline float2v fma2(float2v a, float2v b, float2v c) {
    return __builtin_elementwise_fma(a, b, c);
}
__device__ inline float med3(float a, float b, float c) {
    return __builtin_amdgcn_fmed3f(a, b, c);
}
// branchless sorted-insert of v into b0<=b1<=b2 (3 VALU):
//   b2'=med3(b1,b2,v)  b1'=med3(b0,b1,v)  b0'=min(b0,v)   (old values on RHS)
#define INSERT3(B0, B1, B2, V)                    \
    do { float _v = (V);                          \
         (B2) = med3((B1), (B2), _v);             \
         (B1) = med3((B0), (B1), _v);             \
         (B0) = fminf((B0), _v); } while (0)

// ---------------------------------------------------------------------------
// knn_main: fused gather + top-3. Each block: QPB=1024 queries (4/thread)
// x CHUNK targets staged in LDS (pair-interleaved SoA, -2 folded, ||t||^2
// in .w with BIG sentinel for invalid). Inner loop per target-pair per query:
// 3 v_pk_fma_f32 + 2x3 med3/min = 4.5 VALU/pair; 1 ds_read_b128 per
// 4 pairs -> LDS return BW no longer the bottleneck.
// Distances carried WITHOUT ||s||^2 (ordering-invariant); added at epilogue.
// ---------------------------------------------------------------------------
template <int NCH>
__global__ __launch_bounds__(256) void knn_main(
    const float* __restrict__ src_pc,   // [B,64,2048,3]
    const float* __restrict__ tgt_pc,   // [B,3,64,2048]
    float* __restrict__ partial)        // [NCH][3][NB*NQ] plane-major
{
    constexpr int CHUNK = NQ / NCH;     // targets per chunk
    constexpr int NPAIR = CHUNK / 2;
    __shared__ float4 lt[NPAIR * 2];    // pair p: lt[2p]={X0,X1,Y0,Y1}, lt[2p+1]={Z0,Z1,W0,W1}

    const int tid = threadIdx.x;
    int blk   = blockIdx.x;
    int qt    = blk % QTILES;
    int rest  = blk / QTILES;
    int chunk = rest % NCH;
    int b     = rest / NCH;

    // ---- stage chunk targets into LDS ----
    float* ltf = (float*)lt;
    for (int j = tid; j < CHUNK; j += 256) {
        int tq = chunk * CHUNK + j;
        int oh = tq >> 9, ow = tq & 511;
        size_t base = ((size_t)(b * 3) * IN_H + oh * 2) * IN_W + ow * 4;
        float x = tgt_pc[base];
        float y = tgt_pc[base + (size_t)IN_H * IN_W];
        float z = tgt_pc[base + 2 * (size_t)IN_H * IN_W];
        bool valid = (x != 0.f) || (y != 0.f) || (z != 0.f);
        float w = valid ? (x * x + y * y + z * z) : BIG;
        if (!valid) { x = 0.f; y = 0.f; z = 0.f; }
        float* dst = ltf + (j >> 1) * 8 + (j & 1);
        dst[0] = -2.f * x;
        dst[2] = -2.f * y;
        dst[4] = -2.f * z;
        dst[6] = w;
    }

    // ---- load this thread's 4 queries (direct, strided) ----
    float2v sx[4], sy[4], sz[4];
    float sw[4];
    const int q0 = qt * QPB + tid;
    #pragma unroll
    for (int m = 0; m < 4; ++m) {
        int q = q0 + m * 256;
        int oh = q >> 9, ow = q & 511;
        size_t base = (((size_t)b * IN_H + oh * 2) * IN_W + ow * 4) * 3;
        float x = src_pc[base], y = src_pc[base + 1], z = src_pc[base + 2];
        sx[m] = (float2v){x, x};
        sy[m] = (float2v){y, y};
        sz[m] = (float2v){z, z};
        sw[m] = x * x + y * y + z * z;
    }

    float e0[4], e1[4], e2[4], o0[4], o1[4], o2[4];
    #pragma unroll
    for (int m = 0; m < 4; ++m)
        e0[m] = e1[m] = e2[m] = o0[m] = o1[m] = o2[m] = BIG;

    __syncthreads();

    #pragma unroll 4
    for (int p = 0; p < NPAIR; ++p) {
        float4 A = lt[2 * p];       // broadcast: 0 bank conflicts
        float4 B = lt[2 * p + 1];
        float2v tx = {A.x, A.y};
        float2v ty = {A.z, A.w};
        float2v tz = {B.x, B.y};
        float2v tw = {B.z, B.w};
        #pragma unroll
        for (int m = 0; m < 4; ++m) {
            float2v v = fma2(sx[m], tx, fma2(sy[m], ty, fma2(sz[m], tz, tw)));
            INSERT3(e0[m], e1[m], e2[m], v.x);
            INSERT3(o0[m], o1[m], o2[m], v.y);
        }
    }

    // ---- epilogue: merge odd stream into even, add ||s||^2, write planes ----
    const int NQT = NB * NQ;
    #pragma unroll
    for (int m = 0; m < 4; ++m) {
        float b0 = e0[m], b1 = e1[m], b2 = e2[m];
        INSERT3(b0, b1, b2, o0[m]);
        INSERT3(b0, b1, b2, o1[m]);
        INSERT3(b0, b1, b2, o2[m]);
        int gq = b * NQ + q0 + m * 256;
        partial[(chunk * 3 + 0) * NQT + gq] = b0 + sw[m];
        partial[(chunk * 3 + 1) * NQT + gq] = b1 + sw[m];
        partial[(chunk * 3 + 2) * NQT + gq] = b2 + sw[m];
    }
}

// ---------------------------------------------------------------------------
// merge_final: per query merge NCH chunk-trios, sqrt+clamp, masked reduce,
// per-batch atomics; last finished block computes the scalar output.
// ---------------------------------------------------------------------------
template <int NCH>
__global__ __launch_bounds__(256) void merge_final(
    const float* __restrict__ partial,
    const float* __restrict__ src_pc,
    float* __restrict__ accum,          // [0..3]={sum0,cnt0,sum1,cnt1}
    int* __restrict__ done_cnt,
    float* __restrict__ out)
{
    const int NQT = NB * NQ;
    int gid = blockIdx.x * 256 + threadIdx.x;   // < NQT
    int b = gid >> 14;
    int q = gid & (NQ - 1);

    float b0 = BIG, b1 = BIG, b2 = BIG;
    #pragma unroll
    for (int c = 0; c < NCH * 3; ++c) {
        float v = partial[c * NQT + gid];       // coalesced plane reads
        INSERT3(b0, b1, b2, v);
    }

    int oh = q >> 9, ow = q & 511;
    size_t base = (((size_t)b * IN_H + oh * 2) * IN_W + ow * 4) * 3;
    float x = src_pc[base], y = src_pc[base + 1], z = src_pc[base + 2];
    float w = ((x != 0.f) || (y != 0.f) || (z != 0.f)) ? 1.f : 0.f;

    float d = fminf(sqrtf(fmaxf(b0, 0.f)), 1e10f)
            + fminf(sqrtf(fmaxf(b1, 0.f)), 1e10f)
            + fminf(sqrtf(fmaxf(b2, 0.f)), 1e10f);
    float dsum = d * w;

    #pragma unroll
    for (int off = 32; off > 0; off >>= 1) {
        dsum += __shfl_down(dsum, off, 64);
        w    += __shfl_down(w, off, 64);
    }
    __shared__ float sd[4], sw4[4];
    int lane = threadIdx.x & 63, wv = threadIdx.x >> 6;
    if (lane == 0) { sd[wv] = dsum; sw4[wv] = w; }
    __syncthreads();
    if (threadIdx.x == 0) {
        atomicAdd(&accum[b * 2 + 0], sd[0] + sd[1] + sd[2] + sd[3]);
        atomicAdd(&accum[b * 2 + 1], sw4[0] + sw4[1] + sw4[2] + sw4[3]);
        __threadfence();
        int done = atomicAdd(done_cnt, 1);
        if (done == (int)gridDim.x - 1) {
            // coherent device-scope reads via RMW(+0)
            float s0 = atomicAdd(&accum[0], 0.f);
            float c0 = atomicAdd(&accum[1], 0.f);
            float s1 = atomicAdd(&accum[2], 0.f);
            float c1 = atomicAdd(&accum[3], 0.f);
            float r = s0 / (3.0f * fmaxf(c0, 1.0f))
                    + s1 / (3.0f * fmaxf(c1, 1.0f));
            out[0] = r / (float)NB;
        }
    }
}

// ---------------------------------------------------------------------------
extern "C" void kernel_launch(void* const* d_in, const int* in_sizes, int n_in,
                              void* d_out, int out_size, void* d_ws, size_t ws_size,
                              hipStream_t stream) {
    const float* src_pc = (const float*)d_in[0];   // [2,64,2048,3]
    const float* tgt_pc = (const float*)d_in[1];   // [2,3,64,2048]
    float* out = (float*)d_out;

    char* ws = (char*)d_ws;
    float* accum   = (float*)ws;                    // 4 floats
    int*   done    = (int*)(ws + 32);
    float* partial = (float*)(ws + 64);

    hipMemsetAsync(ws, 0, 64, stream);

    const size_t need16 = 64 + (size_t)16 * 3 * NB * NQ * sizeof(float); // ~6.3 MB
    if (ws_size >= need16) {
        knn_main<16><<<NB * 16 * QTILES, 256, 0, stream>>>(src_pc, tgt_pc, partial);
        merge_final<16><<<NB * NQ / 256, 256, 0, stream>>>(partial, src_pc, accum, done, out);
    } else {
        knn_main<8><<<NB * 8 * QTILES, 256, 0, stream>>>(src_pc, tgt_pc, partial);
        merge_final<8><<<NB * NQ / 256, 256, 0, stream>>>(partial, src_pc, accum, done, out);
    }
}

// Round 4
// 147.055 us; speedup vs baseline: 1.5861x; 1.0016x over previous
//
#include <hip/hip_runtime.h>
#include <math.h>

#define NB 2
#define NQ 16384        // 32*512 downsampled points per batch
#define OUT_W 512
#define IN_H 64
#define IN_W 2048
#define BIG 1e30f
#define QPB 1024        // queries per block = 256 threads * M(4)
#define QTILES (NQ / QPB)   // 16

typedef float float2v __attribute__((ext_vector_type(2)));

__device__ inline float2v fma2(float2v a, float2v b, float2v c) {
    return __builtin_elementwise_fma(a, b, c);
}
__device__ inline float med3(float a, float b, float c) {
    return __builtin_amdgcn_fmed3f(a, b, c);
}
// branchless sorted-insert of v into b0<=b1<=b2 (3 VALU, no deps beyond chain):
#define INSERT3(B0, B1, B2, V)                    \
    do { float _v = (V);                          \
         (B2) = med3((B1), (B2), _v);             \
         (B1) = med3((B0), (B1), _v);             \
         (B0) = fminf((B0), _v); } while (0)

// ---------------------------------------------------------------------------
// knn_main<NCH>: fused gather + top-3 over one target chunk.
// grid = NB * NCH * QTILES blocks of 256 (NCH=32 -> 1024 blocks, 4/CU,
// 16 waves/CU). Each thread: M=4 queries x 2 target streams (even/odd).
// LDS: ltA[p]={X0,X1,Y0,Y1}, ltB[p]={Z0,Z1,W0,W1} per target pair p;
// staged with per-thread ds_write_b128 at 16 B/lane (conflict-free),
// read as wave-uniform b128 broadcasts (conflict-free).
// Distances carried without ||s||^2 (ordering-invariant); added at epilogue.
// ---------------------------------------------------------------------------
template <int NCH>
__global__ __launch_bounds__(256) void knn_main(
    const float* __restrict__ src_pc,   // [B,64,2048,3]
    const float* __restrict__ tgt_pc,   // [B,3,64,2048]
    float* __restrict__ partial)        // [NCH][3][NB*NQ] plane-major
{
    constexpr int CHUNK = NQ / NCH;     // targets per chunk
    constexpr int NPAIR = CHUNK / 2;
    __shared__ float4 ltA[NPAIR];       // {-2x0,-2x1,-2y0,-2y1}
    __shared__ float4 ltB[NPAIR];       // {-2z0,-2z1, w0, w1}

    const int tid = threadIdx.x;
    int blk   = blockIdx.x;
    int qt    = blk % QTILES;
    int rest  = blk / QTILES;
    int chunk = rest % NCH;
    int b     = rest / NCH;

    // ---- stage chunk targets into LDS (one pair per thread-iter) ----
    for (int i = tid; i < NPAIR; i += 256) {
        int tq = chunk * CHUNK + 2 * i;
        int oh = tq >> 9, ow = tq & 511;
        size_t base = ((size_t)(b * 3) * IN_H + oh * 2) * IN_W + ow * 4;
        const size_t PL = (size_t)IN_H * IN_W;
        float x0 = tgt_pc[base],          x1 = tgt_pc[base + 4];
        float y0 = tgt_pc[base + PL],     y1 = tgt_pc[base + PL + 4];
        float z0 = tgt_pc[base + 2 * PL], z1 = tgt_pc[base + 2 * PL + 4];
        bool v0 = (x0 != 0.f) || (y0 != 0.f) || (z0 != 0.f);
        bool v1 = (x1 != 0.f) || (y1 != 0.f) || (z1 != 0.f);
        float w0 = v0 ? (x0 * x0 + y0 * y0 + z0 * z0) : BIG;
        float w1 = v1 ? (x1 * x1 + y1 * y1 + z1 * z1) : BIG;
        if (!v0) { x0 = 0.f; y0 = 0.f; z0 = 0.f; }
        if (!v1) { x1 = 0.f; y1 = 0.f; z1 = 0.f; }
        ltA[i] = make_float4(-2.f * x0, -2.f * x1, -2.f * y0, -2.f * y1);
        ltB[i] = make_float4(-2.f * z0, -2.f * z1, w0, w1);
    }

    // ---- load this thread's 4 queries (direct, strided) ----
    float sxs[4], sys[4], szs[4], sw[4];
    const int q0 = qt * QPB + tid;
    #pragma unroll
    for (int m = 0; m < 4; ++m) {
        int q = q0 + m * 256;
        int oh = q >> 9, ow = q & 511;
        size_t base = (((size_t)b * IN_H + oh * 2) * IN_W + ow * 4) * 3;
        sxs[m] = src_pc[base];
        sys[m] = src_pc[base + 1];
        szs[m] = src_pc[base + 2];
        sw[m] = sxs[m] * sxs[m] + sys[m] * sys[m] + szs[m] * szs[m];
    }

    float e0[4], e1[4], e2[4], o0[4], o1[4], o2[4];
    #pragma unroll
    for (int m = 0; m < 4; ++m)
        e0[m] = e1[m] = e2[m] = o0[m] = o1[m] = o2[m] = BIG;

    __syncthreads();

    #pragma unroll 4
    for (int p = 0; p < NPAIR; ++p) {
        float4 A = ltA[p];              // wave-uniform broadcast b128
        float4 B = ltB[p];
        float2v tx = {A.x, A.y};
        float2v ty = {A.z, A.w};
        float2v tz = {B.x, B.y};
        float2v tw = {B.z, B.w};
        #pragma unroll
        for (int m = 0; m < 4; ++m) {
            float2v sx = {sxs[m], sxs[m]};
            float2v sy = {sys[m], sys[m]};
            float2v sz = {szs[m], szs[m]};
            float2v v = fma2(sx, tx, fma2(sy, ty, fma2(sz, tz, tw)));
            INSERT3(e0[m], e1[m], e2[m], v.x);
            INSERT3(o0[m], o1[m], o2[m], v.y);
        }
    }

    // ---- epilogue: merge odd into even, add ||s||^2, write planes ----
    const int NQT = NB * NQ;
    #pragma unroll
    for (int m = 0; m < 4; ++m) {
        float b0 = e0[m], b1 = e1[m], b2 = e2[m];
        INSERT3(b0, b1, b2, o0[m]);
        INSERT3(b0, b1, b2, o1[m]);
        INSERT3(b0, b1, b2, o2[m]);
        int gq = b * NQ + q0 + m * 256;
        partial[(chunk * 3 + 0) * NQT + gq] = b0 + sw[m];
        partial[(chunk * 3 + 1) * NQT + gq] = b1 + sw[m];
        partial[(chunk * 3 + 2) * NQT + gq] = b2 + sw[m];
    }
}

// ---------------------------------------------------------------------------
// merge_final<NCH>: per query merge chunk trios, sqrt+clamp, masked reduce,
// per-batch atomics; last finished block computes the scalar output.
// ---------------------------------------------------------------------------
template <int NCH>
__global__ __launch_bounds__(256) void merge_final(
    const float* __restrict__ partial,
    const float* __restrict__ src_pc,
    float* __restrict__ accum,          // [0..3]={sum0,cnt0,sum1,cnt1}
    int* __restrict__ done_cnt,
    float* __restrict__ out)
{
    const int NQT = NB * NQ;
    int gid = blockIdx.x * 256 + threadIdx.x;   // < NQT
    int b = gid >> 14;
    int q = gid & (NQ - 1);

    float b0 = BIG, b1 = BIG, b2 = BIG;
    #pragma unroll
    for (int c = 0; c < NCH * 3; ++c) {
        float v = partial[c * NQT + gid];       // coalesced plane reads
        INSERT3(b0, b1, b2, v);
    }

    int oh = q >> 9, ow = q & 511;
    size_t base = (((size_t)b * IN_H + oh * 2) * IN_W + ow * 4) * 3;
    float x = src_pc[base], y = src_pc[base + 1], z = src_pc[base + 2];
    float w = ((x != 0.f) || (y != 0.f) || (z != 0.f)) ? 1.f : 0.f;

    float d = fminf(sqrtf(fmaxf(b0, 0.f)), 1e10f)
            + fminf(sqrtf(fmaxf(b1, 0.f)), 1e10f)
            + fminf(sqrtf(fmaxf(b2, 0.f)), 1e10f);
    float dsum = d * w;

    #pragma unroll
    for (int off = 32; off > 0; off >>= 1) {
        dsum += __shfl_down(dsum, off, 64);
        w    += __shfl_down(w, off, 64);
    }
    __shared__ float sd[4], sw4[4];
    int lane = threadIdx.x & 63, wv = threadIdx.x >> 6;
    if (lane == 0) { sd[wv] = dsum; sw4[wv] = w; }
    __syncthreads();
    if (threadIdx.x == 0) {
        atomicAdd(&accum[b * 2 + 0], sd[0] + sd[1] + sd[2] + sd[3]);
        atomicAdd(&accum[b * 2 + 1], sw4[0] + sw4[1] + sw4[2] + sw4[3]);
        __threadfence();
        int done = atomicAdd(done_cnt, 1);
        if (done == (int)gridDim.x - 1) {
            float s0 = atomicAdd(&accum[0], 0.f);
            float c0 = atomicAdd(&accum[1], 0.f);
            float s1 = atomicAdd(&accum[2], 0.f);
            float c1 = atomicAdd(&accum[3], 0.f);
            float r = s0 / (3.0f * fmaxf(c0, 1.0f))
                    + s1 / (3.0f * fmaxf(c1, 1.0f));
            out[0] = r / (float)NB;
        }
    }
}

// ---------------------------------------------------------------------------
extern "C" void kernel_launch(void* const* d_in, const int* in_sizes, int n_in,
                              void* d_out, int out_size, void* d_ws, size_t ws_size,
                              hipStream_t stream) {
    const float* src_pc = (const float*)d_in[0];   // [2,64,2048,3]
    const float* tgt_pc = (const float*)d_in[1];   // [2,3,64,2048]
    float* out = (float*)d_out;

    char* ws = (char*)d_ws;
    float* accum   = (float*)ws;                    // 4 floats
    int*   done    = (int*)(ws + 32);
    float* partial = (float*)(ws + 64);

    hipMemsetAsync(ws, 0, 64, stream);

    const size_t plane = (size_t)3 * NB * NQ * sizeof(float);  // 393216 B
    if (ws_size >= 64 + 32 * plane) {          // ~12.6 MB
        knn_main<32><<<NB * 32 * QTILES, 256, 0, stream>>>(src_pc, tgt_pc, partial);
        merge_final<32><<<NB * NQ / 256, 256, 0, stream>>>(partial, src_pc, accum, done, out);
    } else if (ws_size >= 64 + 16 * plane) {   // ~6.3 MB
        knn_main<16><<<NB * 16 * QTILES, 256, 0, stream>>>(src_pc, tgt_pc, partial);
        merge_final<16><<<NB * NQ / 256, 256, 0, stream>>>(partial, src_pc, accum, done, out);
    } else {
        knn_main<8><<<NB * 8 * QTILES, 256, 0, stream>>>(src_pc, tgt_pc, partial);
        merge_final<8><<<NB * NQ / 256, 256, 0, stream>>>(partial, src_pc, accum, done, out);
    }
}